// Round 3
// baseline (133.561 us; speedup 1.0000x reference)
//
#include <hip/hip_runtime.h>
#include <cstdint>

#define ND 4096      // N_DRUGS
#define D  512       // W_DIM

typedef __bf16 bf16x8 __attribute__((ext_vector_type(8)));
typedef float floatx4 __attribute__((ext_vector_type(4)));
typedef unsigned short ushort8 __attribute__((ext_vector_type(8)));

__device__ __forceinline__ float bf2f(unsigned short b) {
    return __uint_as_float(((unsigned int)b) << 16);
}
__device__ __forceinline__ unsigned short f2bf(float f) {
    unsigned int u = __float_as_uint(f);
    u += 0x7fffu + ((u >> 16) & 1u);   // RNE
    return (unsigned short)(u >> 16);
}
__device__ __forceinline__ float lo16(unsigned int u) { return __uint_as_float(u << 16); }
__device__ __forceinline__ float hi16(unsigned int u) { return __uint_as_float(u & 0xffff0000u); }

union U8B8 { ushort8 u; bf16x8 b; };

// ---- dtype detection ----------------------------------------------------
// flags[0] = 1 if float tensors are bf16 (else fp32)
// flags[1] = 1 if edge indices are int64 (else int32)
__global__ __launch_bounds__(256) void detect_kernel(const unsigned short* __restrict__ z,
                                                     const int* __restrict__ ed,
                                                     int* __restrict__ flags) {
    __shared__ int c0, c1;
    if (threadIdx.x == 0) { c0 = 0; c1 = 0; }
    __syncthreads();
    // bf16 N(0,1) data: exponent field of every ushort lands in [96,160].
    // fp32 data viewed as ushorts: even words are uniform mantissa bits (~25% in range).
    unsigned short u = z[threadIdx.x];
    int e = (u >> 7) & 0xFF;
    if (e >= 96 && e <= 160) atomicAdd(&c0, 1);
    // int64 edges with values <4096: every odd int32 word is zero.
    if (threadIdx.x < 64 && ed[2 * threadIdx.x + 1] == 0) atomicAdd(&c1, 1);
    __syncthreads();
    if (threadIdx.x == 0) {
        flags[0] = (c0 >= 240) ? 1 : 0;
        flags[1] = (c1 >= 56) ? 1 : 0;
    }
}

// ---- Mt[n][k] = bf16( W[k][n] * d[k] * d[n] ) ---------------------------
__global__ __launch_bounds__(256) void make_mt(const void* __restrict__ Wv,
                                               const void* __restrict__ ldv,
                                               const int* __restrict__ sub,
                                               unsigned short* __restrict__ Mt,
                                               const int* __restrict__ flags) {
    int t = blockIdx.x * 256 + threadIdx.x;
    int n = t >> 9;
    int k = t & (D - 1);
    int su = sub[0];
    if ((unsigned)su > 9u) su = 2;   // safety clamp (valid range 0..9)
    float w, dk, dn;
    if (flags[0]) {
        const unsigned short* W  = (const unsigned short*)Wv;
        const unsigned short* ld = (const unsigned short*)ldv + su * D;
        w = bf2f(W[k * D + n]); dk = bf2f(ld[k]); dn = bf2f(ld[n]);
    } else {
        const float* W  = (const float*)Wv;
        const float* ld = (const float*)ldv + su * D;
        w = W[k * D + n]; dk = ld[k]; dn = ld[n];
    }
    Mt[n * D + k] = f2bf(w * dk * dn);
}

// ---- GEMM: Y[m][n] = bf16( sum_k z[m][k] * Mt[n][k] ) -------------------
template <bool BF>
__device__ __forceinline__ bf16x8 load_a8(const void* z, int row, int col) {
    if constexpr (BF) {
        return *(const bf16x8*)((const __bf16*)z + row * D + col);
    } else {
        const float* zf = (const float*)z + row * D + col;
        float4 f0 = *(const float4*)zf;
        float4 f1 = *(const float4*)(zf + 4);
        U8B8 cv;
        cv.u[0] = f2bf(f0.x); cv.u[1] = f2bf(f0.y); cv.u[2] = f2bf(f0.z); cv.u[3] = f2bf(f0.w);
        cv.u[4] = f2bf(f1.x); cv.u[5] = f2bf(f1.y); cv.u[6] = f2bf(f1.z); cv.u[7] = f2bf(f1.w);
        return cv.b;
    }
}

template <bool BF>
__device__ void gemm_body(const void* __restrict__ z,
                          const unsigned short* __restrict__ Mt,
                          unsigned short* __restrict__ Y) {
    int w = threadIdx.x >> 6;
    int lane = threadIdx.x & 63;
    int rl = lane & 15;
    int quad = lane >> 4;
    int tm = blockIdx.x * 64 + (w >> 1) * 32;
    int tn = blockIdx.y * 64 + (w & 1) * 32;

    floatx4 acc[2][2] = {};
#pragma unroll 4
    for (int kk = 0; kk < D; kk += 32) {
        int ko = kk + quad * 8;
        bf16x8 a0 = load_a8<BF>(z, tm + rl, ko);
        bf16x8 a1 = load_a8<BF>(z, tm + 16 + rl, ko);
        bf16x8 b0 = *(const bf16x8*)((const __bf16*)Mt + (tn + rl) * D + ko);
        bf16x8 b1 = *(const bf16x8*)((const __bf16*)Mt + (tn + 16 + rl) * D + ko);
        acc[0][0] = __builtin_amdgcn_mfma_f32_16x16x32_bf16(a0, b0, acc[0][0], 0, 0, 0);
        acc[0][1] = __builtin_amdgcn_mfma_f32_16x16x32_bf16(a0, b1, acc[0][1], 0, 0, 0);
        acc[1][0] = __builtin_amdgcn_mfma_f32_16x16x32_bf16(a1, b0, acc[1][0], 0, 0, 0);
        acc[1][1] = __builtin_amdgcn_mfma_f32_16x16x32_bf16(a1, b1, acc[1][1], 0, 0, 0);
    }
#pragma unroll
    for (int j = 0; j < 2; j++) {
        int col = tn + j * 16 + rl;              // C/D layout: col = lane&15
#pragma unroll
        for (int i = 0; i < 2; i++) {
            int rbase = tm + i * 16 + quad * 4;  // C/D layout: row = quad*4 + reg
#pragma unroll
            for (int r = 0; r < 4; r++)
                Y[(rbase + r) * D + col] = f2bf(acc[i][j][r]);
        }
    }
}

__global__ __launch_bounds__(256) void gemm_kernel(const void* __restrict__ z,
                                                   const unsigned short* __restrict__ Mt,
                                                   unsigned short* __restrict__ Y,
                                                   const int* __restrict__ flags) {
    if (flags[0]) gemm_body<true>(z, Mt, Y);
    else          gemm_body<false>(z, Mt, Y);
}

// ---- edge: out[e] = sigmoid( dot(Y[r_e], z[c_e]) ) ----------------------
template <bool BF>
__device__ __forceinline__ float dot_y_z(const unsigned short* Y, const void* z,
                                         int r, int c, int lane) {
    uint4 yu = *(const uint4*)(Y + r * D + lane * 8);
    float y0 = lo16(yu.x), y1 = hi16(yu.x), y2 = lo16(yu.y), y3 = hi16(yu.y);
    float y4 = lo16(yu.z), y5 = hi16(yu.z), y6 = lo16(yu.w), y7 = hi16(yu.w);
    float s;
    if constexpr (BF) {
        uint4 zu = *(const uint4*)((const unsigned short*)z + c * D + lane * 8);
        s  = y0 * lo16(zu.x) + y1 * hi16(zu.x);
        s += y2 * lo16(zu.y) + y3 * hi16(zu.y);
        s += y4 * lo16(zu.z) + y5 * hi16(zu.z);
        s += y6 * lo16(zu.w) + y7 * hi16(zu.w);
    } else {
        const float* zf = (const float*)z + c * D + lane * 8;
        float4 f0 = *(const float4*)zf;
        float4 f1 = *(const float4*)(zf + 4);
        s  = y0 * f0.x + y1 * f0.y + y2 * f0.z + y3 * f0.w;
        s += y4 * f1.x + y5 * f1.y + y6 * f1.z + y7 * f1.w;
    }
    return s;
}

__global__ __launch_bounds__(256) void edge_kernel(const unsigned short* __restrict__ Y,
                                                   const void* __restrict__ z,
                                                   const int* __restrict__ ed,
                                                   void* __restrict__ out,
                                                   int E,
                                                   const int* __restrict__ flags) {
    int wid = (blockIdx.x * 256 + threadIdx.x) >> 6;
    int lane = threadIdx.x & 63;
    if (wid >= E) return;
    int bf = flags[0], i64 = flags[1];
    int r, c;
    if (i64) { r = ed[2 * wid]; c = ed[2 * (E + wid)]; }
    else     { r = ed[wid];     c = ed[E + wid]; }
    r &= ND - 1; c &= ND - 1;

    float s = bf ? dot_y_z<true>(Y, z, r, c, lane)
                 : dot_y_z<false>(Y, z, r, c, lane);
#pragma unroll
    for (int off = 32; off; off >>= 1)
        s += __shfl_xor(s, off, 64);

    if (lane == 0) {
        if (!(s > -1e30f && s < 1e30f)) s = 0.0f;   // sanitize NaN/Inf -> finite
        float sig = 1.0f / (1.0f + __expf(-s));
        if (bf) ((unsigned short*)out)[wid] = f2bf(sig);
        else    ((float*)out)[wid] = sig;
    }
}

extern "C" void kernel_launch(void* const* d_in, const int* in_sizes, int n_in,
                              void* d_out, int out_size, void* d_ws, size_t ws_size,
                              hipStream_t stream) {
    const void* z     = d_in[0];            // z_drug [4096,512] bf16 or fp32
    const void* W     = d_in[1];            // global_weight [512,512]
    const void* ldiag = d_in[2];            // local_diag [10,512]
    const int* edges  = (const int*)d_in[3];// batch_edges [2,E] int32 or int64
    const int* sub    = (const int*)d_in[4];// edge_sub_type_idx
    int E = out_size;

    char* ws = (char*)d_ws;
    unsigned short* Y  = (unsigned short*)ws;                         // 4 MB  bf16 [4096,512]
    unsigned short* Mt = (unsigned short*)(ws + (size_t)ND * D * 2);  // 0.5 MB bf16 [512,512]
    int* flags         = (int*)(ws + (size_t)ND * D * 2 + (size_t)D * D * 2);

    detect_kernel<<<1, 256, 0, stream>>>((const unsigned short*)z, edges, flags);
    make_mt<<<(D * D) / 256, 256, 0, stream>>>(W, ldiag, sub, Mt, flags);
    gemm_kernel<<<dim3(ND / 64, D / 64), 256, 0, stream>>>(z, Mt, Y, flags);
    edge_kernel<<<(E + 3) / 4, 256, 0, stream>>>(Y, z, edges, d_out, E, flags);
}

// Round 4
// 122.104 us; speedup vs baseline: 1.0938x; 1.0938x over previous
//
#include <hip/hip_runtime.h>
#include <cstdint>

#define ND 4096      // N_DRUGS
#define D  512       // W_DIM

typedef __bf16 bf16x8 __attribute__((ext_vector_type(8)));
typedef float floatx4 __attribute__((ext_vector_type(4)));
typedef unsigned short ushort8 __attribute__((ext_vector_type(8)));

__device__ __forceinline__ float bf2f(unsigned short b) {
    return __uint_as_float(((unsigned int)b) << 16);
}
__device__ __forceinline__ unsigned short f2bf(float f) {
    unsigned int u = __float_as_uint(f);
    u += 0x7fffu + ((u >> 16) & 1u);   // RNE
    return (unsigned short)(u >> 16);
}
__device__ __forceinline__ float lo16(unsigned int u) { return __uint_as_float(u << 16); }
__device__ __forceinline__ float hi16(unsigned int u) { return __uint_as_float(u & 0xffff0000u); }

__device__ __forceinline__ void gll16(const void* g, void* l) {
    // async global->LDS, 16B/lane; LDS dest = wave-uniform base + lane*16
    __builtin_amdgcn_global_load_lds((const __attribute__((address_space(1))) unsigned int*)g,
                                     (__attribute__((address_space(3))) unsigned int*)l,
                                     16, 0, 0);
}

union U8B8 { ushort8 u; bf16x8 b; };

// ---- dtype detection ----------------------------------------------------
// flags[0] = 1 if float tensors are bf16 (else fp32)
// flags[1] = 1 if edge indices are int64 (else int32)
__global__ __launch_bounds__(256) void detect_kernel(const unsigned short* __restrict__ z,
                                                     const int* __restrict__ ed,
                                                     int* __restrict__ flags) {
    __shared__ int c0, c1;
    if (threadIdx.x == 0) { c0 = 0; c1 = 0; }
    __syncthreads();
    unsigned short u = z[threadIdx.x];
    int e = (u >> 7) & 0xFF;
    if (e >= 96 && e <= 160) atomicAdd(&c0, 1);
    if (threadIdx.x < 64 && ed[2 * threadIdx.x + 1] == 0) atomicAdd(&c1, 1);
    __syncthreads();
    if (threadIdx.x == 0) {
        flags[0] = (c0 >= 240) ? 1 : 0;
        flags[1] = (c1 >= 56) ? 1 : 0;
    }
}

// ---- Mt[n][k] = bf16( W[k][n] * d[k] * d[n] ), coalesced via LDS transpose
__global__ __launch_bounds__(256) void make_mt(const void* __restrict__ Wv,
                                               const void* __restrict__ ldv,
                                               const int* __restrict__ sub,
                                               unsigned short* __restrict__ Mt,
                                               const int* __restrict__ flags) {
    __shared__ float lds[64][65];   // +1 pad: transpose-read conflict-free
    int bf = flags[0];
    int su = sub[0];
    if ((unsigned)su > 9u) su = 2;
    int k0 = blockIdx.x * 64, n0 = blockIdx.y * 64;
    int j = threadIdx.x & 63;       // lane: n-offset on load, k-offset on store
    int w = threadIdx.x >> 6;       // wave id (0..3)

    // load: rows of W (coalesced)
#pragma unroll
    for (int r = 0; r < 16; r++) {
        int k = k0 + w * 16 + r;
        float v = bf ? bf2f(((const unsigned short*)Wv)[k * D + n0 + j])
                     : ((const float*)Wv)[k * D + n0 + j];
        lds[w * 16 + r][j] = v;
    }
    __syncthreads();

    int k = k0 + j;
    float dk = bf ? bf2f(((const unsigned short*)ldv)[su * D + k])
                  : ((const float*)ldv)[su * D + k];
#pragma unroll
    for (int r = 0; r < 16; r++) {
        int n = n0 + w * 16 + r;
        float dn = bf ? bf2f(((const unsigned short*)ldv)[su * D + n])
                      : ((const float*)ldv)[su * D + n];
        Mt[n * D + k] = f2bf(lds[j][w * 16 + r] * dk * dn);  // coalesced in k
    }
}

// ---- GEMM: Y[m][n] = bf16( sum_k z[m][k] * Mt[n][k] ) -------------------
// 64x64 block tile, BK=64 LDS staging (global_load_lds w=16), 4 waves 2x2.
template <bool BF>
__device__ void gemm_body(const void* __restrict__ z,
                          const unsigned short* __restrict__ Mt,
                          unsigned short* __restrict__ Y) {
    __shared__ __bf16 As[64 * 64];
    __shared__ __bf16 Bs[64 * 64];
    int tid = threadIdx.x;
    int w = tid >> 6, lane = tid & 63;
    int rl = lane & 15, quad = lane >> 4;
    int tm = blockIdx.x * 64, tn = blockIdx.y * 64;
    int wm = (w >> 1) * 32, wn = (w & 1) * 32;

    floatx4 acc[2][2] = {};
    for (int kk = 0; kk < D; kk += 64) {
        __syncthreads();   // prior ds_reads done before overwrite
        // stage B (always bf16): wave w -> rows 16w..16w+15 of tile
#pragma unroll
        for (int jj = 0; jj < 2; jj++) {
            int rowB = tn + w * 16 + jj * 8 + (lane >> 3);
            int col  = kk + (lane & 7) * 8;
            gll16(Mt + rowB * D + col, &Bs[(w * 16 + jj * 8) * 64]);
            if constexpr (BF) {
                int rowA = tm + w * 16 + jj * 8 + (lane >> 3);
                gll16((const __bf16*)z + rowA * D + col, &As[(w * 16 + jj * 8) * 64]);
            } else {
                int rowA = tm + w * 16 + jj * 8 + (lane >> 3);
                const float* zf = (const float*)z + rowA * D + col;
                float4 f0 = *(const float4*)zf;
                float4 f1 = *(const float4*)(zf + 4);
                U8B8 cv;
                cv.u[0] = f2bf(f0.x); cv.u[1] = f2bf(f0.y); cv.u[2] = f2bf(f0.z); cv.u[3] = f2bf(f0.w);
                cv.u[4] = f2bf(f1.x); cv.u[5] = f2bf(f1.y); cv.u[6] = f2bf(f1.z); cv.u[7] = f2bf(f1.w);
                *(bf16x8*)&As[(w * 16 + jj * 8 + (lane >> 3)) * 64 + (lane & 7) * 8] = cv.b;
            }
        }
        __syncthreads();   // drains vmcnt (global_load_lds) + lgkmcnt
#pragma unroll
        for (int kc = 0; kc < 64; kc += 32) {
            bf16x8 a0 = *(const bf16x8*)&As[(wm + rl) * 64 + kc + quad * 8];
            bf16x8 a1 = *(const bf16x8*)&As[(wm + 16 + rl) * 64 + kc + quad * 8];
            bf16x8 b0 = *(const bf16x8*)&Bs[(wn + rl) * 64 + kc + quad * 8];
            bf16x8 b1 = *(const bf16x8*)&Bs[(wn + 16 + rl) * 64 + kc + quad * 8];
            acc[0][0] = __builtin_amdgcn_mfma_f32_16x16x32_bf16(a0, b0, acc[0][0], 0, 0, 0);
            acc[0][1] = __builtin_amdgcn_mfma_f32_16x16x32_bf16(a0, b1, acc[0][1], 0, 0, 0);
            acc[1][0] = __builtin_amdgcn_mfma_f32_16x16x32_bf16(a1, b0, acc[1][0], 0, 0, 0);
            acc[1][1] = __builtin_amdgcn_mfma_f32_16x16x32_bf16(a1, b1, acc[1][1], 0, 0, 0);
        }
    }
#pragma unroll
    for (int j = 0; j < 2; j++) {
        int col = tn + wn + j * 16 + rl;              // C/D: col = lane&15
#pragma unroll
        for (int i = 0; i < 2; i++) {
            int rbase = tm + wm + i * 16 + quad * 4;  // C/D: row = quad*4 + reg
#pragma unroll
            for (int r = 0; r < 4; r++)
                Y[(rbase + r) * D + col] = f2bf(acc[i][j][r]);
        }
    }
}

__global__ __launch_bounds__(256) void gemm_kernel(const void* __restrict__ z,
                                                   const unsigned short* __restrict__ Mt,
                                                   unsigned short* __restrict__ Y,
                                                   const int* __restrict__ flags) {
    if (flags[0]) gemm_body<true>(z, Mt, Y);
    else          gemm_body<false>(z, Mt, Y);
}

// ---- edge pass: partial/full dot over D-half, 2 edges per wave ----------
// pass 0: partial[e] = dot(Y[r][0:256], z[c][0:256])
// pass 1: out[e] = sigmoid(partial[e] + dot over [256:512])
__global__ __launch_bounds__(256) void edge_pass(const unsigned short* __restrict__ Y,
                                                 const void* __restrict__ z,
                                                 const int* __restrict__ ed,
                                                 float* __restrict__ partial,
                                                 void* __restrict__ out,
                                                 int E,
                                                 const int* __restrict__ flags,
                                                 int pass) {
    int wid = (blockIdx.x * 256 + threadIdx.x) >> 6;
    int lane = threadIdx.x & 63;
    int h = lane >> 5, l = lane & 31;
    int e = wid * 2 + h;
    if (e >= E) return;
    int bf = flags[0];
    int r, c;
    if (flags[1]) { r = ed[2 * e]; c = ed[2 * (E + e)]; }
    else          { r = ed[e];     c = ed[E + e]; }
    r &= ND - 1; c &= ND - 1;

    int col = pass * 256 + l * 8;
    uint4 yu = *(const uint4*)(Y + r * D + col);
    float y0 = lo16(yu.x), y1 = hi16(yu.x), y2 = lo16(yu.y), y3 = hi16(yu.y);
    float y4 = lo16(yu.z), y5 = hi16(yu.z), y6 = lo16(yu.w), y7 = hi16(yu.w);
    float s;
    if (bf) {
        uint4 zu = *(const uint4*)((const unsigned short*)z + c * D + col);
        s  = y0 * lo16(zu.x) + y1 * hi16(zu.x);
        s += y2 * lo16(zu.y) + y3 * hi16(zu.y);
        s += y4 * lo16(zu.z) + y5 * hi16(zu.z);
        s += y6 * lo16(zu.w) + y7 * hi16(zu.w);
    } else {
        const float* zf = (const float*)z + c * D + col;
        float4 f0 = *(const float4*)zf;
        float4 f1 = *(const float4*)(zf + 4);
        s  = y0 * f0.x + y1 * f0.y + y2 * f0.z + y3 * f0.w;
        s += y4 * f1.x + y5 * f1.y + y6 * f1.z + y7 * f1.w;
    }
#pragma unroll
    for (int off = 16; off; off >>= 1)     // reduce within 32-lane group
        s += __shfl_xor(s, off, 64);

    if (l == 0) {
        if (pass == 0) {
            partial[e] = s;
        } else {
            float t = s + partial[e];
            if (!(t > -1e30f && t < 1e30f)) t = 0.0f;
            float sig = 1.0f / (1.0f + __expf(-t));
            if (bf) ((unsigned short*)out)[e] = f2bf(sig);
            else    ((float*)out)[e] = sig;
        }
    }
}

extern "C" void kernel_launch(void* const* d_in, const int* in_sizes, int n_in,
                              void* d_out, int out_size, void* d_ws, size_t ws_size,
                              hipStream_t stream) {
    const void* z     = d_in[0];             // z_drug [4096,512]
    const void* W     = d_in[1];             // global_weight [512,512]
    const void* ldiag = d_in[2];             // local_diag [10,512]
    const int* edges  = (const int*)d_in[3]; // batch_edges [2,E]
    const int* sub    = (const int*)d_in[4]; // edge_sub_type_idx
    int E = out_size;

    char* ws = (char*)d_ws;
    unsigned short* Y  = (unsigned short*)ws;                          // 4 MB bf16 [4096,512]
    unsigned short* Mt = (unsigned short*)(ws + 4194304);              // 0.5 MB bf16 [512,512]
    int* flags         = (int*)(ws + 4194304 + 524288);                // 256 B
    float* partial     = (float*)(ws + 4194304 + 524288 + 256);        // E*4 B

    detect_kernel<<<1, 256, 0, stream>>>((const unsigned short*)z, edges, flags);
    make_mt<<<dim3(D / 64, D / 64), 256, 0, stream>>>(W, ldiag, sub, Mt, flags);
    gemm_kernel<<<dim3(ND / 64, D / 64), 256, 0, stream>>>(z, Mt, Y, flags);
    int eblocks = (E / 2 + 3) / 4;
    edge_pass<<<eblocks, 256, 0, stream>>>(Y, z, edges, partial, d_out, E, flags, 0);
    edge_pass<<<eblocks, 256, 0, stream>>>(Y, z, edges, partial, d_out, E, flags, 1);
}